// Round 3
// baseline (197.007 us; speedup 1.0000x reference)
//
#include <hip/hip_runtime.h>
#include <stdint.h>
#include <stddef.h>

#define N_SENT 100000
#define N_TYPE 10000
#define NEDGE  640000
#define NROWS  (N_SENT + N_TYPE)
#define MAXDEG 256    // LDS cache per wave in agg_k; Poisson(64): P(deg>256) ~ 0. Fallback exists.
#define HB     64     // histogram chunks; 64 * 10000 == NEDGE exactly
#define HCHUNK (NEDGE / HB)

__device__ __forceinline__ float bf2f(uint32_t lo16) {
    return __builtin_bit_cast(float, lo16 << 16);
}
__device__ __forceinline__ uint32_t f2bf(float f) {
    uint32_t u = __builtin_bit_cast(uint32_t, f);
    return (u + 0x7fffu + ((u >> 16) & 1u)) >> 16;
}

// Inline per-wave dtype probe: bf16 pairs have bf16-sane exponents in the low halfword;
// f32 low halfwords are mantissa bits (uniform). One broadcast load + ballot, wave-uniform.
__device__ __forceinline__ bool detect_bf16(const uint32_t* __restrict__ h) {
    uint32_t u = h[threadIdx.x & 63];
    uint32_t e_lo = (u >> 7) & 0xffu;
    int ok = (e_lo >= 100u && e_lo <= 140u) ? 1 : 0;
    unsigned long long m = __ballot(ok);
    return __popcll(m) >= 48;
}

// ---- fused scores + edge histogram ----
// Blocks [0, HB): per-chunk LDS histogram of dst -> count2[cb][bin] (start first, hide
// under scores). Blocks [HB, HB+SCORE_BLOCKS): 16 rows per wave, 64 rows per block.
// sched_barrier(0) pins all 16 row-loads in flight (round-1 showed the compiler sinks
// the FMAs into the load loop otherwise: VGPR=16, fully serialized vmcnt waits).
#define SCORE_BLOCKS ((NROWS + 63) / 64)   // 1719

__global__ __launch_bounds__(256) void scores_count_k(const void* __restrict__ h_sent,
                                                      const void* __restrict__ h_type,
                                                      const void* __restrict__ attn_w,
                                                      const int* __restrict__ dst,
                                                      float* __restrict__ s_src,
                                                      float* __restrict__ s_dst,
                                                      uint32_t* __restrict__ count2) {
    __shared__ uint32_t hist[N_TYPE];   // 40 KB (used by count blocks only)
    if (blockIdx.x < HB) {
        // ---- count part ----
        int cb = blockIdx.x;
        int t  = threadIdx.x;
        for (int i = t; i < N_TYPE; i += 256) hist[i] = 0u;
        __syncthreads();
        int e0 = cb * HCHUNK;
        for (int i = t; i < HCHUNK; i += 256)
            atomicAdd(&hist[dst[e0 + i]], 1u);
        __syncthreads();
        uint32_t* row = count2 + (size_t)cb * N_TYPE;
        for (int i = t; i < N_TYPE; i += 256) row[i] = hist[i];
        return;
    }
    // ---- scores part ----
    int lane = threadIdx.x & 63;
    int sb   = blockIdx.x - HB;
    int r0   = (sb * 4 + (int)(threadIdx.x >> 6)) * 16;  // first of 16 rows
    bool isbf = detect_bf16((const uint32_t*)h_sent);
    float v[16];
    if (isbf) {
        uint32_t wv_s = ((const uint32_t*)attn_w)[lane];
        uint32_t wv_t = ((const uint32_t*)attn_w)[64 + lane];
        float ws0 = bf2f(wv_s & 0xffffu), ws1 = bf2f(wv_s >> 16);
        float wt0 = bf2f(wv_t & 0xffffu), wt1 = bf2f(wv_t >> 16);
        uint32_t hv[16];
#pragma unroll
        for (int i = 0; i < 16; i++) {           // phase 1: issue all 16 loads
            int g  = r0 + i;
            int gc = g < NROWS ? g : NROWS - 1;  // clamp tail; masked in phase 2
            bool isSrc = gc < N_SENT;
            const uint32_t* hp = isSrc
                ? (const uint32_t*)h_sent + (size_t)gc * 64
                : (const uint32_t*)h_type + (size_t)(gc - N_SENT) * 64;
            hv[i] = hp[lane];
        }
        __builtin_amdgcn_sched_barrier(0);       // keep all 16 loads in flight
#pragma unroll
        for (int i = 0; i < 16; i++) {           // phase 2: FMAs
            int g = r0 + i;
            bool isSrc = g < N_SENT;
            float wa = isSrc ? ws0 : wt0, wb = isSrc ? ws1 : wt1;
            v[i] = (g < NROWS)
                 ? (bf2f(hv[i] & 0xffffu) * wa + bf2f(hv[i] >> 16) * wb)
                 : 0.0f;
        }
    } else {
        float2 wv_s = ((const float2*)attn_w)[lane];
        float2 wv_t = ((const float2*)attn_w)[64 + lane];
        float2 hv[16];
#pragma unroll
        for (int i = 0; i < 16; i++) {           // phase 1: issue all 16 loads
            int g  = r0 + i;
            int gc = g < NROWS ? g : NROWS - 1;
            bool isSrc = gc < N_SENT;
            const float2* hp = isSrc
                ? (const float2*)h_sent + (size_t)gc * 64
                : (const float2*)h_type + (size_t)(gc - N_SENT) * 64;
            hv[i] = hp[lane];
        }
        __builtin_amdgcn_sched_barrier(0);       // keep all 16 loads in flight
#pragma unroll
        for (int i = 0; i < 16; i++) {           // phase 2: FMAs
            int g = r0 + i;
            bool isSrc = g < N_SENT;
            float wa = isSrc ? wv_s.x : wv_t.x, wb = isSrc ? wv_s.y : wv_t.y;
            v[i] = (g < NROWS) ? (hv[i].x * wa + hv[i].y * wb) : 0.0f;
        }
    }
    // fold 16 rows -> 1 value/lane (row = lane&15): merge stages d=1,2,4,8, then butterfly
    int b0 = lane & 1, b1 = (lane >> 1) & 1, b2 = (lane >> 2) & 1, b3 = (lane >> 3) & 1;
    float w_[8];
#pragma unroll
    for (int i = 0; i < 8; i++) {
        float keep = b0 ? v[2 * i + 1] : v[2 * i];
        float send = b0 ? v[2 * i]     : v[2 * i + 1];
        w_[i] = keep + __shfl_xor(send, 1, 64);
    }
    float x_[4];
#pragma unroll
    for (int i = 0; i < 4; i++) {
        float keep = b1 ? w_[2 * i + 1] : w_[2 * i];
        float send = b1 ? w_[2 * i]     : w_[2 * i + 1];
        x_[i] = keep + __shfl_xor(send, 2, 64);
    }
    float y_[2];
#pragma unroll
    for (int i = 0; i < 2; i++) {
        float keep = b2 ? x_[2 * i + 1] : x_[2 * i];
        float send = b2 ? x_[2 * i]     : x_[2 * i + 1];
        y_[i] = keep + __shfl_xor(send, 4, 64);
    }
    float z;
    {
        float keep = b3 ? y_[1] : y_[0];
        float send = b3 ? y_[0] : y_[1];
        z = keep + __shfl_xor(send, 8, 64);
    }
    z += __shfl_xor(z, 16, 64);
    z += __shfl_xor(z, 32, 64);
    if (lane < 16) {
        int g = r0 + lane;
        if (g < NROWS) {
            if (g < N_SENT) s_src[g] = z;
            else            s_dst[g - N_SENT] = z;
        }
    }
}

// ---- column exclusive-scan over chunks, register-resident ----
// 64 independent loads -> register scan -> 64 independent stores.
__global__ __launch_bounds__(256) void sumscan_k(uint32_t* __restrict__ count2,
                                                 uint32_t* __restrict__ total) {
    int b = blockIdx.x * 256 + (int)threadIdx.x;   // bin
    bool ok = b < N_TYPE;
    int bc = ok ? b : N_TYPE - 1;
    uint32_t vals[HB];
#pragma unroll
    for (int c = 0; c < HB; c++)
        vals[c] = count2[(size_t)c * N_TYPE + bc];   // all 64 in flight
    uint32_t run = 0;
#pragma unroll
    for (int c = 0; c < HB; c++) { uint32_t v = vals[c]; vals[c] = run; run += v; }
    if (ok) {
        total[b] = run;
#pragma unroll
        for (int c = 0; c < HB; c++)
            count2[(size_t)c * N_TYPE + b] = vals[c];
    }
}

// ---- fill: in-block exclusive scan of total (redundant per block, parallel & L2-hot),
//      LDS cursors = offsets[bin] + base2[cb][bin], LDS-atomic scatter.
//      Block 0 additionally publishes offsets[] for agg_k. Kills the 1-block scan_k.
__global__ __launch_bounds__(256) void fill_k(const int* __restrict__ src,
                                              const int* __restrict__ dst,
                                              const uint32_t* __restrict__ total,
                                              const uint32_t* __restrict__ base2,
                                              uint32_t* __restrict__ offsets,
                                              uint32_t* __restrict__ edge_src) {
    __shared__ uint32_t cur[N_TYPE];   // 40 KB
    __shared__ uint32_t wsum[4];
    const int CH = 40;                 // 256*40 >= N_TYPE
    int cb = blockIdx.x;               // [0, HB)
    int t  = threadIdx.x, lane = t & 63, wv = t >> 6;   // 4 waves
    int base = t * CH;
    uint32_t local[CH];
    uint32_t tsum = 0;
#pragma unroll
    for (int i = 0; i < CH; i++) {
        int idx = base + i;
        uint32_t c = (idx < N_TYPE) ? total[idx] : 0u;
        local[i] = c;
        tsum += c;
    }
    uint32_t orig = tsum;
#pragma unroll
    for (int off = 1; off < 64; off <<= 1) {
        uint32_t v = __shfl_up(tsum, off, 64);
        if (lane >= off) tsum += v;
    }
    if (lane == 63) wsum[wv] = tsum;
    __syncthreads();
    uint32_t wbase = 0;
#pragma unroll
    for (int w = 0; w < 4; w++) wbase += (w < wv) ? wsum[w] : 0u;
    uint32_t run = wbase + tsum - orig;   // exclusive prefix of total at bin `base`
    const uint32_t* brow = base2 + (size_t)cb * N_TYPE;
#pragma unroll
    for (int i = 0; i < CH; i++) {
        int idx = base + i;
        if (idx < N_TYPE) {
            cur[idx] = run + brow[idx];
            if (cb == 0) offsets[idx] = run;
        }
        run += local[i];
    }
    if (cb == 0 && t == 255) offsets[N_TYPE] = run;   // == NEDGE
    __syncthreads();
    int e0 = cb * HCHUNK;
    for (int i = t; i < HCHUNK; i += 256) {
        int e = e0 + i;
        uint32_t pos = atomicAdd(&cur[dst[e]], 1u);   // LDS-only atomic
        edge_src[pos] = (uint32_t)src[e];
    }
}

// ---- one wave per destination: max -> exp-weighted gather-sum (x8 unrolled) -> normalize
__global__ __launch_bounds__(256) void agg_k(const void* __restrict__ h_sent,
                                             const void* __restrict__ h_type,
                                             const float* __restrict__ s_src,
                                             const float* __restrict__ s_dst,
                                             const uint32_t* __restrict__ offsets,
                                             const uint32_t* __restrict__ edge_src,
                                             void* __restrict__ out) {
    __shared__ float    sc[4][MAXDEG];
    __shared__ uint32_t ss[4][MAXDEG];
    int j     = (blockIdx.x * 256 + threadIdx.x) >> 6;
    int wslot = threadIdx.x >> 6;
    int lane  = threadIdx.x & 63;
    bool valid = j < N_TYPE;
    bool isbf  = detect_bf16((const uint32_t*)h_sent);
    uint32_t beg = 0, deg = 0;
    float sdj = 0.0f;
    if (valid) {
        beg = offsets[j];
        deg = offsets[j + 1] - beg;
        sdj = s_dst[j];
    }
    float*    mysc = sc[wslot];
    uint32_t* myss = ss[wslot];
    bool fits = (deg <= MAXDEG);
    float m = -INFINITY;
    for (uint32_t k = lane; k < deg; k += 64) {
        uint32_t s = edge_src[beg + k];
        float v = s_src[s] + sdj;
        v = v > 0.0f ? v : 0.01f * v;
        if (fits) { mysc[k] = v; myss[k] = s; }
        m = fmaxf(m, v);
    }
#pragma unroll
    for (int off = 32; off; off >>= 1) m = fmaxf(m, __shfl_xor(m, off, 64));
    __syncthreads();   // LDS visibility (uniform: every thread reaches this)
    if (!valid) return;
    if (deg == 0) {    // isolated node keeps its input feature
        if (isbf) ((uint32_t*)out)[(size_t)j * 64 + lane] =
                      ((const uint32_t*)h_type)[(size_t)j * 64 + lane];
        else      ((float2*)out)[(size_t)j * 64 + lane] =
                      ((const float2*)h_type)[(size_t)j * 64 + lane];
        return;
    }
    float denom = 0.0f, a0 = 0.0f, a1 = 0.0f;
    if (isbf) {
        const uint32_t* hp = (const uint32_t*)h_sent;
        uint32_t k = 0;
        if (fits) {
            for (; k + 8 <= deg; k += 8) {
                uint32_t sv[8]; float vv[8]; uint32_t gv[8];
#pragma unroll
                for (int i = 0; i < 8; i++) { sv[i] = myss[k + i]; vv[i] = mysc[k + i]; }
#pragma unroll
                for (int i = 0; i < 8; i++) gv[i] = hp[(size_t)sv[i] * 64 + lane];
#pragma unroll
                for (int i = 0; i < 8; i++) {
                    float w = __expf(vv[i] - m);
                    denom += w;
                    a0 += w * bf2f(gv[i] & 0xffffu);
                    a1 += w * bf2f(gv[i] >> 16);
                }
            }
            for (; k < deg; ++k) {
                float w = __expf(mysc[k] - m);
                uint32_t g = hp[(size_t)myss[k] * 64 + lane];
                denom += w;
                a0 += w * bf2f(g & 0xffffu);
                a1 += w * bf2f(g >> 16);
            }
        } else {
            for (k = 0; k < deg; ++k) {
                uint32_t s = edge_src[beg + k];
                float v = s_src[s] + sdj; v = v > 0.0f ? v : 0.01f * v;
                float w = __expf(v - m);
                uint32_t g = hp[(size_t)s * 64 + lane];
                denom += w;
                a0 += w * bf2f(g & 0xffffu);
                a1 += w * bf2f(g >> 16);
            }
        }
        float inv = 1.0f / denom;
        ((uint32_t*)out)[(size_t)j * 64 + lane] = f2bf(a0 * inv) | (f2bf(a1 * inv) << 16);
    } else {
        const float2* hp = (const float2*)h_sent;
        uint32_t k = 0;
        if (fits) {
            for (; k + 8 <= deg; k += 8) {
                uint32_t sv[8]; float vv[8]; float2 gv[8];
#pragma unroll
                for (int i = 0; i < 8; i++) { sv[i] = myss[k + i]; vv[i] = mysc[k + i]; }
#pragma unroll
                for (int i = 0; i < 8; i++) gv[i] = hp[(size_t)sv[i] * 64 + lane];
#pragma unroll
                for (int i = 0; i < 8; i++) {
                    float w = __expf(vv[i] - m);
                    denom += w;
                    a0 += w * gv[i].x;
                    a1 += w * gv[i].y;
                }
            }
            for (; k < deg; ++k) {
                float w = __expf(mysc[k] - m);
                float2 g = hp[(size_t)myss[k] * 64 + lane];
                denom += w;
                a0 += w * g.x;
                a1 += w * g.y;
            }
        } else {
            for (k = 0; k < deg; ++k) {
                uint32_t s = edge_src[beg + k];
                float v = s_src[s] + sdj; v = v > 0.0f ? v : 0.01f * v;
                float w = __expf(v - m);
                float2 g = hp[(size_t)s * 64 + lane];
                denom += w;
                a0 += w * g.x;
                a1 += w * g.y;
            }
        }
        float inv = 1.0f / denom;
        ((float2*)out)[(size_t)j * 64 + lane] = make_float2(a0 * inv, a1 * inv);
    }
}

static inline size_t align_up(size_t x) { return (x + 255) & ~(size_t)255; }

extern "C" void kernel_launch(void* const* d_in, const int* in_sizes, int n_in,
                              void* d_out, int out_size, void* d_ws, size_t ws_size,
                              hipStream_t stream) {
    const void* h_sent = d_in[0];
    const void* h_type = d_in[1];
    const void* attn_w = d_in[2];
    const int* src_idx = (const int*)d_in[3];
    const int* dst_idx = (const int*)d_in[4];

    char* w = (char*)d_ws;
    float*    s_src     = (float*)w;    w += align_up((size_t)N_SENT * 4);
    float*    s_dst     = (float*)w;    w += align_up((size_t)N_TYPE * 4);
    uint32_t* count2    = (uint32_t*)w; w += align_up((size_t)HB * N_TYPE * 4);  // 2.56 MB
    uint32_t* total     = (uint32_t*)w; w += align_up((size_t)N_TYPE * 4);
    uint32_t* offsets   = (uint32_t*)w; w += align_up((size_t)(N_TYPE + 1) * 4);
    uint32_t* edge_src  = (uint32_t*)w; w += align_up((size_t)NEDGE * 4);
    // total ~5.7 MB

    scores_count_k<<<HB + SCORE_BLOCKS, 256, 0, stream>>>(h_sent, h_type, attn_w,
                                                          dst_idx, s_src, s_dst, count2);
    sumscan_k<<<(N_TYPE + 255) / 256, 256, 0, stream>>>(count2, total);
    fill_k<<<HB, 256, 0, stream>>>(src_idx, dst_idx, total, count2, offsets, edge_src);
    agg_k<<<(N_TYPE + 3) / 4, 256, 0, stream>>>(h_sent, h_type, s_src, s_dst,
                                                offsets, edge_src, d_out);
}

// Round 4
// 174.996 us; speedup vs baseline: 1.1258x; 1.1258x over previous
//
#include <hip/hip_runtime.h>
#include <stdint.h>
#include <stddef.h>

#define N_SENT 100000
#define N_TYPE 10000
#define NEDGE  640000
#define NROWS  (N_SENT + N_TYPE)
#define MAXDEG 256    // LDS cache per wave in agg_k; Poisson(64): P(deg>256) ~ 0. Fallback exists.
#define HB     256    // histogram chunks; 256 * 2500 == NEDGE exactly
#define HCHUNK (NEDGE / HB)   // 2500

__device__ __forceinline__ float bf2f(uint32_t lo16) {
    return __builtin_bit_cast(float, lo16 << 16);
}
__device__ __forceinline__ uint32_t f2bf(float f) {
    uint32_t u = __builtin_bit_cast(uint32_t, f);
    return (u + 0x7fffu + ((u >> 16) & 1u)) >> 16;
}

// Inline per-wave dtype probe: bf16 pairs have bf16-sane exponents in the low halfword;
// f32 low halfwords are mantissa bits (uniform). One broadcast load + ballot, wave-uniform.
__device__ __forceinline__ bool detect_bf16(const uint32_t* __restrict__ h) {
    uint32_t u = h[threadIdx.x & 63];
    uint32_t e_lo = (u >> 7) & 0xffu;
    int ok = (e_lo >= 100u && e_lo <= 140u) ? 1 : 0;
    unsigned long long m = __ballot(ok);
    return __popcll(m) >= 48;
}

// ---- scores: 16 rows per wave, 64 rows per block; two-phase loads (MLP) ----
#define SCORE_BLOCKS ((NROWS + 63) / 64)   // 1719

__global__ __launch_bounds__(256) void scores_k(const void* __restrict__ h_sent,
                                                const void* __restrict__ h_type,
                                                const void* __restrict__ attn_w,
                                                float* __restrict__ s_src,
                                                float* __restrict__ s_dst) {
    int lane = threadIdx.x & 63;
    int r0   = (blockIdx.x * 4 + (int)(threadIdx.x >> 6)) * 16;  // first of 16 rows
    bool isbf = detect_bf16((const uint32_t*)h_sent);
    float v[16];
    if (isbf) {
        uint32_t wv_s = ((const uint32_t*)attn_w)[lane];
        uint32_t wv_t = ((const uint32_t*)attn_w)[64 + lane];
        float ws0 = bf2f(wv_s & 0xffffu), ws1 = bf2f(wv_s >> 16);
        float wt0 = bf2f(wv_t & 0xffffu), wt1 = bf2f(wv_t >> 16);
        uint32_t hv[16];
#pragma unroll
        for (int i = 0; i < 16; i++) {           // phase 1: issue all 16 loads
            int g  = r0 + i;
            int gc = g < NROWS ? g : NROWS - 1;  // clamp tail; masked in phase 2
            bool isSrc = gc < N_SENT;
            const uint32_t* hp = isSrc
                ? (const uint32_t*)h_sent + (size_t)gc * 64
                : (const uint32_t*)h_type + (size_t)(gc - N_SENT) * 64;
            hv[i] = hp[lane];
        }
        __builtin_amdgcn_sched_barrier(0);       // keep all 16 loads in flight
#pragma unroll
        for (int i = 0; i < 16; i++) {           // phase 2: FMAs
            int g = r0 + i;
            bool isSrc = g < N_SENT;
            float wa = isSrc ? ws0 : wt0, wb = isSrc ? ws1 : wt1;
            v[i] = (g < NROWS)
                 ? (bf2f(hv[i] & 0xffffu) * wa + bf2f(hv[i] >> 16) * wb)
                 : 0.0f;
        }
    } else {
        float2 wv_s = ((const float2*)attn_w)[lane];
        float2 wv_t = ((const float2*)attn_w)[64 + lane];
        float2 hv[16];
#pragma unroll
        for (int i = 0; i < 16; i++) {           // phase 1: issue all 16 loads
            int g  = r0 + i;
            int gc = g < NROWS ? g : NROWS - 1;
            bool isSrc = gc < N_SENT;
            const float2* hp = isSrc
                ? (const float2*)h_sent + (size_t)gc * 64
                : (const float2*)h_type + (size_t)(gc - N_SENT) * 64;
            hv[i] = hp[lane];
        }
        __builtin_amdgcn_sched_barrier(0);       // keep all 16 loads in flight
#pragma unroll
        for (int i = 0; i < 16; i++) {           // phase 2: FMAs
            int g = r0 + i;
            bool isSrc = g < N_SENT;
            float wa = isSrc ? wv_s.x : wv_t.x, wb = isSrc ? wv_s.y : wv_t.y;
            v[i] = (g < NROWS) ? (hv[i].x * wa + hv[i].y * wb) : 0.0f;
        }
    }
    // fold 16 rows -> 1 value/lane (row = lane&15): merge stages d=1,2,4,8, then butterfly
    int b0 = lane & 1, b1 = (lane >> 1) & 1, b2 = (lane >> 2) & 1, b3 = (lane >> 3) & 1;
    float w_[8];
#pragma unroll
    for (int i = 0; i < 8; i++) {
        float keep = b0 ? v[2 * i + 1] : v[2 * i];
        float send = b0 ? v[2 * i]     : v[2 * i + 1];
        w_[i] = keep + __shfl_xor(send, 1, 64);
    }
    float x_[4];
#pragma unroll
    for (int i = 0; i < 4; i++) {
        float keep = b1 ? w_[2 * i + 1] : w_[2 * i];
        float send = b1 ? w_[2 * i]     : w_[2 * i + 1];
        x_[i] = keep + __shfl_xor(send, 2, 64);
    }
    float y_[2];
#pragma unroll
    for (int i = 0; i < 2; i++) {
        float keep = b2 ? x_[2 * i + 1] : x_[2 * i];
        float send = b2 ? x_[2 * i]     : x_[2 * i + 1];
        y_[i] = keep + __shfl_xor(send, 4, 64);
    }
    float z;
    {
        float keep = b3 ? y_[1] : y_[0];
        float send = b3 ? y_[0] : y_[1];
        z = keep + __shfl_xor(send, 8, 64);
    }
    z += __shfl_xor(z, 16, 64);
    z += __shfl_xor(z, 32, 64);
    if (lane < 16) {
        int g = r0 + lane;
        if (g < NROWS) {
            if (g < N_SENT) s_src[g] = z;
            else            s_dst[g - N_SENT] = z;
        }
    }
}

// ---- count: 256 blocks x 2500-edge chunk; upfront dst loads (MLP), uint4 writeback ----
__global__ __launch_bounds__(256) void count_k(const int* __restrict__ dst,
                                               uint32_t* __restrict__ count2) {
    __shared__ uint32_t hist[N_TYPE];   // 40 KB
    int cb = blockIdx.x;                // [0, HB)
    int t  = threadIdx.x;
#pragma unroll
    for (int i = 0; i < 40; i++) {      // 40*256 >= N_TYPE
        int idx = i * 256 + t;
        if (idx < N_TYPE) hist[idx] = 0u;
    }
    __syncthreads();
    int e0 = cb * HCHUNK;
    int dv[10];                          // HCHUNK = 2500 <= 10*256
#pragma unroll
    for (int k = 0; k < 10; k++) {
        int i = k * 256 + t;
        dv[k] = dst[e0 + (i < HCHUNK ? i : HCHUNK - 1)];
    }
    __builtin_amdgcn_sched_barrier(0);   // all 10 loads in flight
#pragma unroll
    for (int k = 0; k < 10; k++) {
        int i = k * 256 + t;
        if (i < HCHUNK) atomicAdd(&hist[dv[k]], 1u);
    }
    __syncthreads();
    uint4* row = (uint4*)(count2 + (size_t)cb * N_TYPE);
#pragma unroll
    for (int i = 0; i < 10; i++) {       // 2500 uint4 = 10000 words
        int idx = i * 256 + t;
        if (idx < N_TYPE / 4) row[idx] = ((const uint4*)hist)[idx];
    }
}

// ---- column exclusive-scan over 256 chunks, 4 register batches of 64 ----
__global__ __launch_bounds__(256) void sumscan_k(uint32_t* __restrict__ count2,
                                                 uint32_t* __restrict__ total) {
    int b = blockIdx.x * 256 + (int)threadIdx.x;   // bin
    bool ok = b < N_TYPE;
    int bc = ok ? b : N_TYPE - 1;
    uint32_t run = 0;
#pragma unroll
    for (int g = 0; g < HB / 64; g++) {
        uint32_t vals[64];
#pragma unroll
        for (int c = 0; c < 64; c++)                       // 64 independent loads
            vals[c] = count2[(size_t)(g * 64 + c) * N_TYPE + bc];
        __builtin_amdgcn_sched_barrier(0);
#pragma unroll
        for (int c = 0; c < 64; c++) { uint32_t v = vals[c]; vals[c] = run; run += v; }
        if (ok) {
#pragma unroll
            for (int c = 0; c < 64; c++)                   // 64 independent stores
                count2[(size_t)(g * 64 + c) * N_TYPE + b] = vals[c];
        }
    }
    if (ok) total[b] = run;
}

// ---- single-block exclusive scan of totals -> offsets[N_TYPE+1] ----
__global__ __launch_bounds__(1024) void scan_k(const uint32_t* __restrict__ total,
                                               uint32_t* __restrict__ offsets) {
    const int CH = 10;   // 1024*10 >= N_TYPE
    int t = threadIdx.x, lane = t & 63, wv = t >> 6;   // 16 waves
    int base = t * CH;
    uint32_t local[CH];
    uint32_t tsum = 0;
#pragma unroll
    for (int i = 0; i < CH; i++) {
        int idx = base + i;
        uint32_t c = (idx < N_TYPE) ? total[idx] : 0u;
        local[i] = c;
        tsum += c;
    }
    uint32_t orig = tsum;
#pragma unroll
    for (int off = 1; off < 64; off <<= 1) {
        uint32_t v = __shfl_up(tsum, off, 64);
        if (lane >= off) tsum += v;
    }
    __shared__ uint32_t wsum[16];
    if (lane == 63) wsum[wv] = tsum;
    __syncthreads();
    if (wv == 0 && lane < 16) {
        uint32_t u = wsum[lane], o = u;
#pragma unroll
        for (int off = 1; off < 16; off <<= 1) {
            uint32_t v = __shfl_up(u, off, 64);
            if (lane >= off) u += v;
        }
        wsum[lane] = u - o;   // exclusive wave prefix
    }
    __syncthreads();
    uint32_t run = wsum[wv] + tsum - orig;   // exclusive thread prefix
#pragma unroll
    for (int i = 0; i < CH; i++) {
        int idx = base + i;
        if (idx < N_TYPE) {
            offsets[idx] = run;
            run += local[i];
        } else if (idx == N_TYPE) {
            offsets[idx] = run;   // == NEDGE
        }
    }
}

// ---- fill: 256 blocks; uint4 cursor init; upfront edge loads; LDS-atomic scatter ----
__global__ __launch_bounds__(256) void fill_k(const int* __restrict__ src,
                                              const int* __restrict__ dst,
                                              const uint32_t* __restrict__ offsets,
                                              const uint32_t* __restrict__ base2,
                                              uint32_t* __restrict__ edge_src) {
    __shared__ uint32_t cur[N_TYPE];   // 40 KB
    int cb = blockIdx.x;               // [0, HB)
    int t  = threadIdx.x;
    const uint32_t* brow = base2 + (size_t)cb * N_TYPE;
#pragma unroll
    for (int i = 0; i < 10; i++) {     // 2500 uint4 covers 10000 bins
        int idx = i * 256 + t;
        if (idx < N_TYPE / 4) {
            uint4 o = ((const uint4*)offsets)[idx];
            uint4 b = ((const uint4*)brow)[idx];
            uint4 c; c.x = o.x + b.x; c.y = o.y + b.y; c.z = o.z + b.z; c.w = o.w + b.w;
            ((uint4*)cur)[idx] = c;
        }
    }
    __syncthreads();
    int e0 = cb * HCHUNK;
    int dv[10], sv[10];
#pragma unroll
    for (int k = 0; k < 10; k++) {      // all 20 loads upfront
        int i = k * 256 + t;
        int e = e0 + (i < HCHUNK ? i : HCHUNK - 1);
        dv[k] = dst[e];
        sv[k] = src[e];
    }
    __builtin_amdgcn_sched_barrier(0);
#pragma unroll
    for (int k = 0; k < 10; k++) {
        int i = k * 256 + t;
        if (i < HCHUNK) {
            uint32_t pos = atomicAdd(&cur[dv[k]], 1u);   // LDS-only atomic
            edge_src[pos] = (uint32_t)sv[k];
        }
    }
}

// ---- one wave per destination: max -> exp-weighted gather-sum (x8 unrolled) -> normalize
__global__ __launch_bounds__(256) void agg_k(const void* __restrict__ h_sent,
                                             const void* __restrict__ h_type,
                                             const float* __restrict__ s_src,
                                             const float* __restrict__ s_dst,
                                             const uint32_t* __restrict__ offsets,
                                             const uint32_t* __restrict__ edge_src,
                                             void* __restrict__ out) {
    __shared__ float    sc[4][MAXDEG];
    __shared__ uint32_t ss[4][MAXDEG];
    int j     = (blockIdx.x * 256 + threadIdx.x) >> 6;
    int wslot = threadIdx.x >> 6;
    int lane  = threadIdx.x & 63;
    bool valid = j < N_TYPE;
    bool isbf  = detect_bf16((const uint32_t*)h_sent);
    uint32_t beg = 0, deg = 0;
    float sdj = 0.0f;
    if (valid) {
        beg = offsets[j];
        deg = offsets[j + 1] - beg;
        sdj = s_dst[j];
    }
    float*    mysc = sc[wslot];
    uint32_t* myss = ss[wslot];
    bool fits = (deg <= MAXDEG);
    float m = -INFINITY;
    for (uint32_t k = lane; k < deg; k += 64) {
        uint32_t s = edge_src[beg + k];
        float v = s_src[s] + sdj;
        v = v > 0.0f ? v : 0.01f * v;
        if (fits) { mysc[k] = v; myss[k] = s; }
        m = fmaxf(m, v);
    }
#pragma unroll
    for (int off = 32; off; off >>= 1) m = fmaxf(m, __shfl_xor(m, off, 64));
    __syncthreads();   // LDS visibility (uniform: every thread reaches this)
    if (!valid) return;
    if (deg == 0) {    // isolated node keeps its input feature
        if (isbf) ((uint32_t*)out)[(size_t)j * 64 + lane] =
                      ((const uint32_t*)h_type)[(size_t)j * 64 + lane];
        else      ((float2*)out)[(size_t)j * 64 + lane] =
                      ((const float2*)h_type)[(size_t)j * 64 + lane];
        return;
    }
    float denom = 0.0f, a0 = 0.0f, a1 = 0.0f;
    if (isbf) {
        const uint32_t* hp = (const uint32_t*)h_sent;
        uint32_t k = 0;
        if (fits) {
            for (; k + 8 <= deg; k += 8) {
                uint32_t sv[8]; float vv[8]; uint32_t gv[8];
#pragma unroll
                for (int i = 0; i < 8; i++) { sv[i] = myss[k + i]; vv[i] = mysc[k + i]; }
#pragma unroll
                for (int i = 0; i < 8; i++) gv[i] = hp[(size_t)sv[i] * 64 + lane];
#pragma unroll
                for (int i = 0; i < 8; i++) {
                    float w = __expf(vv[i] - m);
                    denom += w;
                    a0 += w * bf2f(gv[i] & 0xffffu);
                    a1 += w * bf2f(gv[i] >> 16);
                }
            }
            for (; k < deg; ++k) {
                float w = __expf(mysc[k] - m);
                uint32_t g = hp[(size_t)myss[k] * 64 + lane];
                denom += w;
                a0 += w * bf2f(g & 0xffffu);
                a1 += w * bf2f(g >> 16);
            }
        } else {
            for (k = 0; k < deg; ++k) {
                uint32_t s = edge_src[beg + k];
                float v = s_src[s] + sdj; v = v > 0.0f ? v : 0.01f * v;
                float w = __expf(v - m);
                uint32_t g = hp[(size_t)s * 64 + lane];
                denom += w;
                a0 += w * bf2f(g & 0xffffu);
                a1 += w * bf2f(g >> 16);
            }
        }
        float inv = 1.0f / denom;
        ((uint32_t*)out)[(size_t)j * 64 + lane] = f2bf(a0 * inv) | (f2bf(a1 * inv) << 16);
    } else {
        const float2* hp = (const float2*)h_sent;
        uint32_t k = 0;
        if (fits) {
            for (; k + 8 <= deg; k += 8) {
                uint32_t sv[8]; float vv[8]; float2 gv[8];
#pragma unroll
                for (int i = 0; i < 8; i++) { sv[i] = myss[k + i]; vv[i] = mysc[k + i]; }
#pragma unroll
                for (int i = 0; i < 8; i++) gv[i] = hp[(size_t)sv[i] * 64 + lane];
#pragma unroll
                for (int i = 0; i < 8; i++) {
                    float w = __expf(vv[i] - m);
                    denom += w;
                    a0 += w * gv[i].x;
                    a1 += w * gv[i].y;
                }
            }
            for (; k < deg; ++k) {
                float w = __expf(mysc[k] - m);
                float2 g = hp[(size_t)myss[k] * 64 + lane];
                denom += w;
                a0 += w * g.x;
                a1 += w * g.y;
            }
        } else {
            for (k = 0; k < deg; ++k) {
                uint32_t s = edge_src[beg + k];
                float v = s_src[s] + sdj; v = v > 0.0f ? v : 0.01f * v;
                float w = __expf(v - m);
                float2 g = hp[(size_t)s * 64 + lane];
                denom += w;
                a0 += w * g.x;
                a1 += w * g.y;
            }
        }
        float inv = 1.0f / denom;
        ((float2*)out)[(size_t)j * 64 + lane] = make_float2(a0 * inv, a1 * inv);
    }
}

static inline size_t align_up(size_t x) { return (x + 255) & ~(size_t)255; }

extern "C" void kernel_launch(void* const* d_in, const int* in_sizes, int n_in,
                              void* d_out, int out_size, void* d_ws, size_t ws_size,
                              hipStream_t stream) {
    const void* h_sent = d_in[0];
    const void* h_type = d_in[1];
    const void* attn_w = d_in[2];
    const int* src_idx = (const int*)d_in[3];
    const int* dst_idx = (const int*)d_in[4];

    char* w = (char*)d_ws;
    float*    s_src     = (float*)w;    w += align_up((size_t)N_SENT * 4);
    float*    s_dst     = (float*)w;    w += align_up((size_t)N_TYPE * 4);
    uint32_t* count2    = (uint32_t*)w; w += align_up((size_t)HB * N_TYPE * 4);  // 10.24 MB
    uint32_t* total     = (uint32_t*)w; w += align_up((size_t)N_TYPE * 4);
    uint32_t* offsets   = (uint32_t*)w; w += align_up((size_t)(N_TYPE + 1) * 4);
    uint32_t* edge_src  = (uint32_t*)w; w += align_up((size_t)NEDGE * 4);
    // total ~13.4 MB

    scores_k<<<SCORE_BLOCKS, 256, 0, stream>>>(h_sent, h_type, attn_w, s_src, s_dst);
    count_k<<<HB, 256, 0, stream>>>(dst_idx, count2);
    sumscan_k<<<(N_TYPE + 255) / 256, 256, 0, stream>>>(count2, total);
    scan_k<<<1, 1024, 0, stream>>>(total, offsets);
    fill_k<<<HB, 256, 0, stream>>>(src_idx, dst_idx, offsets, count2, edge_src);
    agg_k<<<(N_TYPE + 3) / 4, 256, 0, stream>>>(h_sent, h_type, s_src, s_dst,
                                                offsets, edge_src, d_out);
}

// Round 5
// 174.730 us; speedup vs baseline: 1.1275x; 1.0015x over previous
//
#include <hip/hip_runtime.h>
#include <stdint.h>
#include <stddef.h>

#define N_SENT 100000
#define N_TYPE 10000
#define NEDGE  640000
#define NROWS  (N_SENT + N_TYPE)
#define MAXDEG 256    // LDS cache per wave in agg_k; Poisson(64): P(deg>256) ~ 0. Fallback exists.
#define HB     256    // histogram chunks; 256 * 2500 == NEDGE exactly
#define HCHUNK (NEDGE / HB)   // 2500

__device__ __forceinline__ float bf2f(uint32_t lo16) {
    return __builtin_bit_cast(float, lo16 << 16);
}
__device__ __forceinline__ uint32_t f2bf(float f) {
    uint32_t u = __builtin_bit_cast(uint32_t, f);
    return (u + 0x7fffu + ((u >> 16) & 1u)) >> 16;
}

// Inline per-wave dtype probe: bf16 pairs have bf16-sane exponents in the low halfword;
// f32 low halfwords are mantissa bits (uniform). One broadcast load + ballot, wave-uniform.
__device__ __forceinline__ bool detect_bf16(const uint32_t* __restrict__ h) {
    uint32_t u = h[threadIdx.x & 63];
    uint32_t e_lo = (u >> 7) & 0xffu;
    int ok = (e_lo >= 100u && e_lo <= 140u) ? 1 : 0;
    unsigned long long m = __ballot(ok);
    return __popcll(m) >= 48;
}

// ---- scores v2: streaming matvec. One 16B chunk per thread-item; 16 lanes/row (bf16)
// or 32 lanes/row (f32); shfl_xor tree reduce; one scattered 4B store per row.
// Grid is sized so bf16 = exactly 1 item/thread, f32 = exactly 2 items/thread.
#define SC_BLOCKS 6875   // 6875*256 = 1,760,000 = NROWS*16 (bf16 chunks) = (NROWS*32)/2 (f32)

__global__ __launch_bounds__(256) void scores_k(const void* __restrict__ h_sent,
                                                const void* __restrict__ h_type,
                                                const void* __restrict__ attn_w,
                                                float* __restrict__ s_src,
                                                float* __restrict__ s_dst) {
    int t    = blockIdx.x * 256 + (int)threadIdx.x;
    int lane = threadIdx.x & 63;
    bool isbf = detect_bf16((const uint32_t*)h_sent);
    if (isbf) {
        // chunk = t & 15 == lane & 15 (grid stride is a multiple of 64)
        uint4 wsv = ((const uint4*)attn_w)[lane & 15];        // 8 bf16 dims of w[:D]
        uint4 wtv = ((const uint4*)attn_w)[16 + (lane & 15)]; // 8 bf16 dims of w[D:]
        bool isSrc = t < N_SENT * 16;
        const uint4* p = isSrc ? (const uint4*)h_sent + t
                               : (const uint4*)h_type + (t - N_SENT * 16);
        uint4 h = *p;
        uint4 wv = isSrc ? wsv : wtv;
        float s = bf2f(h.x & 0xffffu) * bf2f(wv.x & 0xffffu)
                + bf2f(h.x >> 16)     * bf2f(wv.x >> 16)
                + bf2f(h.y & 0xffffu) * bf2f(wv.y & 0xffffu)
                + bf2f(h.y >> 16)     * bf2f(wv.y >> 16)
                + bf2f(h.z & 0xffffu) * bf2f(wv.z & 0xffffu)
                + bf2f(h.z >> 16)     * bf2f(wv.z >> 16)
                + bf2f(h.w & 0xffffu) * bf2f(wv.w & 0xffffu)
                + bf2f(h.w >> 16)     * bf2f(wv.w >> 16);
        s += __shfl_xor(s, 1, 64);
        s += __shfl_xor(s, 2, 64);
        s += __shfl_xor(s, 4, 64);
        s += __shfl_xor(s, 8, 64);
        if ((lane & 15) == 0) {
            int row = t >> 4;
            if (row < N_SENT) s_src[row] = s;
            else              s_dst[row - N_SENT] = s;
        }
    } else {
        float4 wsv = ((const float4*)attn_w)[lane & 31];        // 4 f32 dims of w[:D]
        float4 wtv = ((const float4*)attn_w)[32 + (lane & 31)]; // 4 f32 dims of w[D:]
        const int HALF = NROWS * 16;   // 1,760,000; items total = NROWS*32
        int it0 = t, it1 = t + HALF;   // both ≡ lane (mod 32)
        bool s0 = it0 < N_SENT * 32, s1 = it1 < N_SENT * 32;
        const float4* p0 = s0 ? (const float4*)h_sent + it0
                              : (const float4*)h_type + (it0 - N_SENT * 32);
        const float4* p1 = s1 ? (const float4*)h_sent + it1
                              : (const float4*)h_type + (it1 - N_SENT * 32);
        float4 h0 = *p0;
        float4 h1 = *p1;
        __builtin_amdgcn_sched_barrier(0);   // both loads in flight
        float4 w0 = s0 ? wsv : wtv, w1 = s1 ? wsv : wtv;
        float a = h0.x * w0.x + h0.y * w0.y + h0.z * w0.z + h0.w * w0.w;
        float b = h1.x * w1.x + h1.y * w1.y + h1.z * w1.z + h1.w * w1.w;
        a += __shfl_xor(a, 1, 64);  b += __shfl_xor(b, 1, 64);
        a += __shfl_xor(a, 2, 64);  b += __shfl_xor(b, 2, 64);
        a += __shfl_xor(a, 4, 64);  b += __shfl_xor(b, 4, 64);
        a += __shfl_xor(a, 8, 64);  b += __shfl_xor(b, 8, 64);
        a += __shfl_xor(a, 16, 64); b += __shfl_xor(b, 16, 64);
        if ((lane & 31) == 0) {
            int r0 = it0 >> 5, r1 = it1 >> 5;
            if (r0 < N_SENT) s_src[r0] = a; else s_dst[r0 - N_SENT] = a;
            if (r1 < N_SENT) s_src[r1] = b; else s_dst[r1 - N_SENT] = b;
        }
    }
}

// ---- count: 256 blocks x 2500-edge chunk; upfront dst loads (MLP), uint4 writeback ----
__global__ __launch_bounds__(256) void count_k(const int* __restrict__ dst,
                                               uint32_t* __restrict__ count2) {
    __shared__ uint32_t hist[N_TYPE];   // 40 KB
    int cb = blockIdx.x;                // [0, HB)
    int t  = threadIdx.x;
#pragma unroll
    for (int i = 0; i < 40; i++) {      // 40*256 >= N_TYPE
        int idx = i * 256 + t;
        if (idx < N_TYPE) hist[idx] = 0u;
    }
    __syncthreads();
    int e0 = cb * HCHUNK;
    int dv[10];                          // HCHUNK = 2500 <= 10*256
#pragma unroll
    for (int k = 0; k < 10; k++) {
        int i = k * 256 + t;
        dv[k] = dst[e0 + (i < HCHUNK ? i : HCHUNK - 1)];
    }
    __builtin_amdgcn_sched_barrier(0);   // all 10 loads in flight
#pragma unroll
    for (int k = 0; k < 10; k++) {
        int i = k * 256 + t;
        if (i < HCHUNK) atomicAdd(&hist[dv[k]], 1u);
    }
    __syncthreads();
    uint4* row = (uint4*)(count2 + (size_t)cb * N_TYPE);
#pragma unroll
    for (int i = 0; i < 10; i++) {       // 2500 uint4 = 10000 words
        int idx = i * 256 + t;
        if (idx < N_TYPE / 4) row[idx] = ((const uint4*)hist)[idx];
    }
}

// ---- column exclusive-scan over 256 chunks, 4 register batches of 64 ----
__global__ __launch_bounds__(256) void sumscan_k(uint32_t* __restrict__ count2,
                                                 uint32_t* __restrict__ total) {
    int b = blockIdx.x * 256 + (int)threadIdx.x;   // bin
    bool ok = b < N_TYPE;
    int bc = ok ? b : N_TYPE - 1;
    uint32_t run = 0;
#pragma unroll
    for (int g = 0; g < HB / 64; g++) {
        uint32_t vals[64];
#pragma unroll
        for (int c = 0; c < 64; c++)                       // 64 independent loads
            vals[c] = count2[(size_t)(g * 64 + c) * N_TYPE + bc];
        __builtin_amdgcn_sched_barrier(0);
#pragma unroll
        for (int c = 0; c < 64; c++) { uint32_t v = vals[c]; vals[c] = run; run += v; }
        if (ok) {
#pragma unroll
            for (int c = 0; c < 64; c++)                   // 64 independent stores
                count2[(size_t)(g * 64 + c) * N_TYPE + b] = vals[c];
        }
    }
    if (ok) total[b] = run;
}

// ---- single-block exclusive scan of totals -> offsets[N_TYPE+1] ----
__global__ __launch_bounds__(1024) void scan_k(const uint32_t* __restrict__ total,
                                               uint32_t* __restrict__ offsets) {
    const int CH = 10;   // 1024*10 >= N_TYPE
    int t = threadIdx.x, lane = t & 63, wv = t >> 6;   // 16 waves
    int base = t * CH;
    uint32_t local[CH];
    uint32_t tsum = 0;
#pragma unroll
    for (int i = 0; i < CH; i++) {
        int idx = base + i;
        uint32_t c = (idx < N_TYPE) ? total[idx] : 0u;
        local[i] = c;
        tsum += c;
    }
    uint32_t orig = tsum;
#pragma unroll
    for (int off = 1; off < 64; off <<= 1) {
        uint32_t v = __shfl_up(tsum, off, 64);
        if (lane >= off) tsum += v;
    }
    __shared__ uint32_t wsum[16];
    if (lane == 63) wsum[wv] = tsum;
    __syncthreads();
    if (wv == 0 && lane < 16) {
        uint32_t u = wsum[lane], o = u;
#pragma unroll
        for (int off = 1; off < 16; off <<= 1) {
            uint32_t v = __shfl_up(u, off, 64);
            if (lane >= off) u += v;
        }
        wsum[lane] = u - o;   // exclusive wave prefix
    }
    __syncthreads();
    uint32_t run = wsum[wv] + tsum - orig;   // exclusive thread prefix
#pragma unroll
    for (int i = 0; i < CH; i++) {
        int idx = base + i;
        if (idx < N_TYPE) {
            offsets[idx] = run;
            run += local[i];
        } else if (idx == N_TYPE) {
            offsets[idx] = run;   // == NEDGE
        }
    }
}

// ---- fill: 256 blocks; uint4 cursor init; upfront edge loads; LDS-atomic scatter ----
__global__ __launch_bounds__(256) void fill_k(const int* __restrict__ src,
                                              const int* __restrict__ dst,
                                              const uint32_t* __restrict__ offsets,
                                              const uint32_t* __restrict__ base2,
                                              uint32_t* __restrict__ edge_src) {
    __shared__ uint32_t cur[N_TYPE];   // 40 KB
    int cb = blockIdx.x;               // [0, HB)
    int t  = threadIdx.x;
    const uint32_t* brow = base2 + (size_t)cb * N_TYPE;
#pragma unroll
    for (int i = 0; i < 10; i++) {     // 2500 uint4 covers 10000 bins
        int idx = i * 256 + t;
        if (idx < N_TYPE / 4) {
            uint4 o = ((const uint4*)offsets)[idx];
            uint4 b = ((const uint4*)brow)[idx];
            uint4 c; c.x = o.x + b.x; c.y = o.y + b.y; c.z = o.z + b.z; c.w = o.w + b.w;
            ((uint4*)cur)[idx] = c;
        }
    }
    __syncthreads();
    int e0 = cb * HCHUNK;
    int dv[10], sv[10];
#pragma unroll
    for (int k = 0; k < 10; k++) {      // all 20 loads upfront
        int i = k * 256 + t;
        int e = e0 + (i < HCHUNK ? i : HCHUNK - 1);
        dv[k] = dst[e];
        sv[k] = src[e];
    }
    __builtin_amdgcn_sched_barrier(0);
#pragma unroll
    for (int k = 0; k < 10; k++) {
        int i = k * 256 + t;
        if (i < HCHUNK) {
            uint32_t pos = atomicAdd(&cur[dv[k]], 1u);   // LDS-only atomic
            edge_src[pos] = (uint32_t)sv[k];
        }
    }
}

// ---- one wave per destination: max -> exp-weighted gather-sum (x16/x8) -> normalize
__global__ __launch_bounds__(256) void agg_k(const void* __restrict__ h_sent,
                                             const void* __restrict__ h_type,
                                             const float* __restrict__ s_src,
                                             const float* __restrict__ s_dst,
                                             const uint32_t* __restrict__ offsets,
                                             const uint32_t* __restrict__ edge_src,
                                             void* __restrict__ out) {
    __shared__ float    sc[4][MAXDEG];
    __shared__ uint32_t ss[4][MAXDEG];
    int j     = (blockIdx.x * 256 + threadIdx.x) >> 6;
    int wslot = threadIdx.x >> 6;
    int lane  = threadIdx.x & 63;
    bool valid = j < N_TYPE;
    bool isbf  = detect_bf16((const uint32_t*)h_sent);
    uint32_t beg = 0, deg = 0;
    float sdj = 0.0f;
    if (valid) {
        beg = offsets[j];
        deg = offsets[j + 1] - beg;
        sdj = s_dst[j];
    }
    float*    mysc = sc[wslot];
    uint32_t* myss = ss[wslot];
    bool fits = (deg <= MAXDEG);
    float m = -INFINITY;
    for (uint32_t k = lane; k < deg; k += 64) {
        uint32_t s = edge_src[beg + k];
        float v = s_src[s] + sdj;
        v = v > 0.0f ? v : 0.01f * v;
        if (fits) { mysc[k] = v; myss[k] = s; }
        m = fmaxf(m, v);
    }
#pragma unroll
    for (int off = 32; off; off >>= 1) m = fmaxf(m, __shfl_xor(m, off, 64));
    __syncthreads();   // LDS visibility (uniform: every thread reaches this)
    if (!valid) return;
    if (deg == 0) {    // isolated node keeps its input feature
        if (isbf) ((uint32_t*)out)[(size_t)j * 64 + lane] =
                      ((const uint32_t*)h_type)[(size_t)j * 64 + lane];
        else      ((float2*)out)[(size_t)j * 64 + lane] =
                      ((const float2*)h_type)[(size_t)j * 64 + lane];
        return;
    }
    float denom = 0.0f, a0 = 0.0f, a1 = 0.0f;
    if (isbf) {
        const uint32_t* hp = (const uint32_t*)h_sent;
        uint32_t k = 0;
        if (fits) {
            for (; k + 16 <= deg; k += 16) {               // 16 row-loads in flight
                uint32_t sv[16]; float vv[16]; uint32_t gv[16];
#pragma unroll
                for (int i = 0; i < 16; i++) { sv[i] = myss[k + i]; vv[i] = mysc[k + i]; }
#pragma unroll
                for (int i = 0; i < 16; i++) gv[i] = hp[(size_t)sv[i] * 64 + lane];
#pragma unroll
                for (int i = 0; i < 16; i++) {
                    float w = __expf(vv[i] - m);
                    denom += w;
                    a0 += w * bf2f(gv[i] & 0xffffu);
                    a1 += w * bf2f(gv[i] >> 16);
                }
            }
            for (; k + 8 <= deg; k += 8) {                 // 8-wide cleanup
                uint32_t sv[8]; float vv[8]; uint32_t gv[8];
#pragma unroll
                for (int i = 0; i < 8; i++) { sv[i] = myss[k + i]; vv[i] = mysc[k + i]; }
#pragma unroll
                for (int i = 0; i < 8; i++) gv[i] = hp[(size_t)sv[i] * 64 + lane];
#pragma unroll
                for (int i = 0; i < 8; i++) {
                    float w = __expf(vv[i] - m);
                    denom += w;
                    a0 += w * bf2f(gv[i] & 0xffffu);
                    a1 += w * bf2f(gv[i] >> 16);
                }
            }
            for (; k < deg; ++k) {
                float w = __expf(mysc[k] - m);
                uint32_t g = hp[(size_t)myss[k] * 64 + lane];
                denom += w;
                a0 += w * bf2f(g & 0xffffu);
                a1 += w * bf2f(g >> 16);
            }
        } else {
            for (k = 0; k < deg; ++k) {
                uint32_t s = edge_src[beg + k];
                float v = s_src[s] + sdj; v = v > 0.0f ? v : 0.01f * v;
                float w = __expf(v - m);
                uint32_t g = hp[(size_t)s * 64 + lane];
                denom += w;
                a0 += w * bf2f(g & 0xffffu);
                a1 += w * bf2f(g >> 16);
            }
        }
        float inv = 1.0f / denom;
        ((uint32_t*)out)[(size_t)j * 64 + lane] = f2bf(a0 * inv) | (f2bf(a1 * inv) << 16);
    } else {
        const float2* hp = (const float2*)h_sent;
        uint32_t k = 0;
        if (fits) {
            for (; k + 16 <= deg; k += 16) {               // 16 row-loads in flight
                uint32_t sv[16]; float vv[16]; float2 gv[16];
#pragma unroll
                for (int i = 0; i < 16; i++) { sv[i] = myss[k + i]; vv[i] = mysc[k + i]; }
#pragma unroll
                for (int i = 0; i < 16; i++) gv[i] = hp[(size_t)sv[i] * 64 + lane];
#pragma unroll
                for (int i = 0; i < 16; i++) {
                    float w = __expf(vv[i] - m);
                    denom += w;
                    a0 += w * gv[i].x;
                    a1 += w * gv[i].y;
                }
            }
            for (; k + 8 <= deg; k += 8) {                 // 8-wide cleanup
                uint32_t sv[8]; float vv[8]; float2 gv[8];
#pragma unroll
                for (int i = 0; i < 8; i++) { sv[i] = myss[k + i]; vv[i] = mysc[k + i]; }
#pragma unroll
                for (int i = 0; i < 8; i++) gv[i] = hp[(size_t)sv[i] * 64 + lane];
#pragma unroll
                for (int i = 0; i < 8; i++) {
                    float w = __expf(vv[i] - m);
                    denom += w;
                    a0 += w * gv[i].x;
                    a1 += w * gv[i].y;
                }
            }
            for (; k < deg; ++k) {
                float w = __expf(mysc[k] - m);
                float2 g = hp[(size_t)myss[k] * 64 + lane];
                denom += w;
                a0 += w * g.x;
                a1 += w * g.y;
            }
        } else {
            for (k = 0; k < deg; ++k) {
                uint32_t s = edge_src[beg + k];
                float v = s_src[s] + sdj; v = v > 0.0f ? v : 0.01f * v;
                float w = __expf(v - m);
                float2 g = hp[(size_t)s * 64 + lane];
                denom += w;
                a0 += w * g.x;
                a1 += w * g.y;
            }
        }
        float inv = 1.0f / denom;
        ((float2*)out)[(size_t)j * 64 + lane] = make_float2(a0 * inv, a1 * inv);
    }
}

static inline size_t align_up(size_t x) { return (x + 255) & ~(size_t)255; }

extern "C" void kernel_launch(void* const* d_in, const int* in_sizes, int n_in,
                              void* d_out, int out_size, void* d_ws, size_t ws_size,
                              hipStream_t stream) {
    const void* h_sent = d_in[0];
    const void* h_type = d_in[1];
    const void* attn_w = d_in[2];
    const int* src_idx = (const int*)d_in[3];
    const int* dst_idx = (const int*)d_in[4];

    char* w = (char*)d_ws;
    float*    s_src     = (float*)w;    w += align_up((size_t)N_SENT * 4);
    float*    s_dst     = (float*)w;    w += align_up((size_t)N_TYPE * 4);
    uint32_t* count2    = (uint32_t*)w; w += align_up((size_t)HB * N_TYPE * 4);  // 10.24 MB
    uint32_t* total     = (uint32_t*)w; w += align_up((size_t)N_TYPE * 4);
    uint32_t* offsets   = (uint32_t*)w; w += align_up((size_t)(N_TYPE + 1) * 4);
    uint32_t* edge_src  = (uint32_t*)w; w += align_up((size_t)NEDGE * 4);
    // total ~13.4 MB

    scores_k<<<SC_BLOCKS, 256, 0, stream>>>(h_sent, h_type, attn_w, s_src, s_dst);
    count_k<<<HB, 256, 0, stream>>>(dst_idx, count2);
    sumscan_k<<<(N_TYPE + 255) / 256, 256, 0, stream>>>(count2, total);
    scan_k<<<1, 1024, 0, stream>>>(total, offsets);
    fill_k<<<HB, 256, 0, stream>>>(src_idx, dst_idx, offsets, count2, edge_src);
    agg_k<<<(N_TYPE + 3) / 4, 256, 0, stream>>>(h_sent, h_type, s_src, s_dst,
                                                offsets, edge_src, d_out);
}